// Round 6
// baseline (548.008 us; speedup 1.0000x reference)
//
#include <hip/hip_runtime.h>
#include <hip/hip_bf16.h>
#include <stdint.h>

// ---------------------------------------------------------------------------
// Fused (base+LoRA) QKV projection -> MHA with bool mask -> out proj.
// B=8 S=1024 D=1024 H=8 DK=128 R=16.  Inputs fp32 (device-detected, bf16
// fallback).  Internal pipeline fp16 (bf16 fails absmax: scores sigma~11, no
// 1/sqrt(dk)).  reshape(nb,H,-1,DK) is a FLAT VIEW: head = contiguous chunk.
// R5->R6: attn QBLK=128/8 waves (2 blk/CU = 16 waves/CU, was 8) + T13
// defer-max (skip O-rescale unless tile max grows >8); projection GEMM
// reg-stages A with fused fp32->f16 convert (3 convert kernels removed),
// q/k/v merged into one z=3 launch.
// ---------------------------------------------------------------------------

#define kB 8
#define kS 1024
#define kD 1024
#define kH 8
#define kDK 128
#define kHDK 1024
#define kM (kB * kS)                       // 8192
#define kMaskWords (kB * kS * (kS / 64))   // 131072 uint64 words
#define kQKVN (kM * kHDK)                  // 8388608 elements

typedef _Float16 f16;
typedef __attribute__((ext_vector_type(4))) float f32x4;
typedef __attribute__((ext_vector_type(8))) _Float16 f16x8;
typedef __attribute__((ext_vector_type(8))) __bf16 bf16x8;

// ws layout (bytes)
#define OFF_FLAG  ((size_t)0)                                   // flags[0]=mask width, flags[1]=fp32?
#define OFF_MBITS ((size_t)256)
#define OFF_WQT   (OFF_MBITS + (size_t)kMaskWords * 8)
#define OFF_WKT   (OFF_WQT + (size_t)2097152)
#define OFF_WVT   (OFF_WKT + (size_t)2097152)
#define OFF_WOT   (OFF_WVT + (size_t)2097152)
#define OFF_Q     (OFF_WOT + (size_t)2097152)
#define OFF_K     (OFF_Q  + (size_t)kQKVN * 2)
#define OFF_VT    (OFF_K  + (size_t)kQKVN * 2)
#define OFF_X     (OFF_VT + (size_t)kQKVN * 2)

__device__ __forceinline__ void async_load16(const void* g, void* lds_uniform) {
  auto gp = reinterpret_cast<const __attribute__((address_space(1))) unsigned int*>(
      reinterpret_cast<uintptr_t>(g));
  auto lp = reinterpret_cast<__attribute__((address_space(3))) unsigned int*>(
      reinterpret_cast<uintptr_t>(lds_uniform));
  __builtin_amdgcn_global_load_lds(gp, lp, 16, 0, 0);
}

__device__ __forceinline__ f32x4 mfma16(f16x8 a, f16x8 b, f32x4 c) {
  return __builtin_amdgcn_mfma_f32_16x16x32_f16(a, b, c, 0, 0, 0);
}

// flag-based scalar read of a float tensor that is fp32 (f=1) or bf16 (f=0)
__device__ __forceinline__ float ldw(const void* p, size_t i, int f) {
  return f ? ((const float*)p)[i] : (float)((const __bf16*)p)[i];
}

// ---------------------------------------------------------------------------
// Detect (wave-parallel): flags[1]=fp32?, flags[0]=mask elem width (1/2/4 B).
// ---------------------------------------------------------------------------
__global__ void detect_kernel(const unsigned int* __restrict__ qw,
                              const unsigned int* __restrict__ mw,
                              int* __restrict__ flags) {
  const int lane = threadIdx.x & 63;
  int hi = 0; bool w4 = true, b1 = true;
  #pragma unroll
  for (int j = 0; j < 4; ++j) {
    unsigned int w = qw[lane * 4 + j];
    hi += (int)(((w >> 7) & 0xFF) > 0x90) + (int)(((w >> 23) & 0xFF) > 0x90);
    unsigned int m = mw[lane * 4 + j];
    if (!(m == 0u || m == 1u || m == 0x3F800000u)) w4 = false;
    if ((m & 0xFEFEFEFEu) != 0u) b1 = false;
  }
  #pragma unroll
  for (int off = 32; off; off >>= 1) hi += __shfl_xor(hi, off, 64);
  unsigned long long bw4 = __ballot(w4), bb1 = __ballot(b1);
  if (lane == 0 && blockIdx.x == 0) {
    flags[1] = (hi > 16) ? 1 : 0;
    flags[0] = (bw4 == ~0ull) ? 4 : ((bb1 == ~0ull) ? 1 : 2);
  }
}

// Pack mask into bit-words: word wi covers mask flat elements [wi*64, wi*64+64)
__global__ void pack_mask_kernel(const void* __restrict__ mask, const int* __restrict__ flags,
                                 unsigned long long* __restrict__ mbits) {
  int wi = blockIdx.x * 4 + (threadIdx.x >> 6);
  if (wi >= kMaskWords) return;
  int lane = threadIdx.x & 63;
  size_t e = (size_t)wi * 64 + lane;
  int width = flags[0];
  bool on;
  if (width == 1)      on = ((const unsigned char*)mask)[e] != 0;
  else if (width == 2) on = ((const unsigned short*)mask)[e] != 0;
  else                 on = ((const unsigned int*)mask)[e] != 0;
  unsigned long long bal = __ballot(on);
  if (lane == 0) mbits[wi] = bal;
}

// ---------------------------------------------------------------------------
// Effective transposed weights: WeffT[n][k] = W[k][n] + sum_r A[k][r]B[r][n]
// ---------------------------------------------------------------------------
__global__ __launch_bounds__(256) void build_weights_kernel(
    const void* __restrict__ Wq, const void* __restrict__ WA, const void* __restrict__ WB,
    const void* __restrict__ Wk, const void* __restrict__ WC, const void* __restrict__ WD,
    const void* __restrict__ Wv, const void* __restrict__ WE, const void* __restrict__ WF,
    const void* __restrict__ Wo, const int* __restrict__ flags,
    f16* __restrict__ WqT, f16* __restrict__ WkT,
    f16* __restrict__ WvT, f16* __restrict__ WoT) {
  const int z = blockIdx.z;
  const int f = flags[1];
  const void *W, *Aw = nullptr, *Bw = nullptr;
  f16* Out;
  if (z == 0)      { W = Wq; Aw = WA; Bw = WB; Out = WqT; }
  else if (z == 1) { W = Wk; Aw = WC; Bw = WD; Out = WkT; }
  else if (z == 2) { W = Wv; Aw = WE; Bw = WF; Out = WvT; }
  else             { W = Wo;                   Out = WoT; }

  __shared__ float Wt[32][33];
  __shared__ float At[32][16];
  __shared__ float Bt[16][33];
  const int tx = threadIdx.x, ty = threadIdx.y;     // block (32,8)
  const int k0 = blockIdx.y * 32, n0 = blockIdx.x * 32;
  #pragma unroll
  for (int i = 0; i < 4; ++i)
    Wt[ty + 8 * i][tx] = ldw(W, (size_t)(k0 + ty + 8 * i) * 1024 + n0 + tx, f);
  const int t = ty * 32 + tx;
  if (Aw) {
    #pragma unroll
    for (int j = 0; j < 2; ++j) {
      int e = t + j * 256;                          // 512 elems: 32x16
      At[e >> 4][e & 15] = ldw(Aw, (size_t)(k0 + (e >> 4)) * 16 + (e & 15), f);
    }
    #pragma unroll
    for (int j = 0; j < 2; ++j) {
      int e = t + j * 256;                          // 512 elems: 16x32
      Bt[e >> 5][e & 31] = ldw(Bw, (size_t)(e >> 5) * 1024 + n0 + (e & 31), f);
    }
  }
  __syncthreads();
  #pragma unroll
  for (int i = 0; i < 4; ++i) {
    const int nloc = ty + 8 * i, kloc = tx;
    float acc = Wt[kloc][nloc];
    if (Aw) {
      #pragma unroll
      for (int r = 0; r < 16; ++r) acc += At[kloc][r] * Bt[r][nloc];
    }
    Out[(size_t)(n0 + nloc) * 1024 + k0 + kloc] = (f16)acc;
  }
}

// ---------------------------------------------------------------------------
// Projection GEMM (z=0/1/2 = q/k/v): C = cvt_f16(A_in) @ BT^T + bias.
// A reg-staged with fused fp32/bf16 -> f16 convert, swizzled ds_write.
// z==2 scatters C into V^T [b][h][d][s].  128x128 tile, BK=32, 4 waves.
// LDS swizzle (both paths): chunk (row,piece) stored at piece^((row>>1)&3).
// ---------------------------------------------------------------------------
__global__ __launch_bounds__(256) void proj_gemm_kernel(
    const void* __restrict__ A0, const void* __restrict__ A1, const void* __restrict__ A2,
    const f16* __restrict__ B0, const f16* __restrict__ B1, const f16* __restrict__ B2,
    const void* __restrict__ b0, const void* __restrict__ b1, const void* __restrict__ b2,
    f16* __restrict__ C0, f16* __restrict__ C1, f16* __restrict__ C2,
    const int* __restrict__ flags) {
  const int z = blockIdx.z;
  const void* A  = (z == 0) ? A0 : (z == 1) ? A1 : A2;
  const f16* BT  = (z == 0) ? B0 : (z == 1) ? B1 : B2;
  const void* bias = (z == 0) ? b0 : (z == 1) ? b1 : b2;
  f16* C = (z == 0) ? C0 : (z == 1) ? C1 : C2;
  const int vtrans = (z == 2);

  __shared__ __align__(16) f16 As[128 * 32];
  __shared__ __align__(16) f16 Bs[128 * 32];

  const int f = flags[1];
  const int tid = threadIdx.x;
  const int lane = tid & 63, w = tid >> 6;
  const int wr = w >> 1, wc = w & 1;
  const int m0 = blockIdx.y * 128;
  const int n0 = blockIdx.x * 128;
  const int l15 = lane & 15, hi = lane >> 4;
  const int swr = (l15 >> 1) & 3;                 // read-side XOR value

  f32x4 acc[4][4];
  #pragma unroll
  for (int i = 0; i < 4; ++i)
    #pragma unroll
    for (int j = 0; j < 4; ++j) acc[i][j] = (f32x4){0.f, 0.f, 0.f, 0.f};

  for (int k0 = 0; k0 < 1024; k0 += 32) {
    // A: issue global->reg loads (targets regs; safe before the barrier)
    f16x8 areg[2];
    #pragma unroll
    for (int j = 0; j < 2; ++j) {
      int c = tid + j * 256;                      // 512 chunks: row=c>>2, piece=c&3
      int row = c >> 2, piece = c & 3;
      if (f) {
        const float* src = (const float*)A + (size_t)(m0 + row) * 1024 + k0 + piece * 8;
        f32x4 a = *(const f32x4*)src;
        f32x4 b = *(const f32x4*)(src + 4);
        #pragma unroll
        for (int e = 0; e < 4; ++e) { areg[j][e] = (f16)a[e]; areg[j][4 + e] = (f16)b[e]; }
      } else {
        const __bf16* src = (const __bf16*)A + (size_t)(m0 + row) * 1024 + k0 + piece * 8;
        bf16x8 a = *(const bf16x8*)src;
        #pragma unroll
        for (int e = 0; e < 8; ++e) areg[j][e] = (f16)(float)a[e];
      }
    }
    if (k0) __syncthreads();                      // prev-tile reads done
    // B: async global->LDS, pre-swizzled source
    #pragma unroll
    for (int j = 0; j < 2; ++j) {
      int c = tid + j * 256;
      int cs = c ^ ((c >> 3) & 3);
      int row = cs >> 2, piece = cs & 3;
      async_load16(BT + (size_t)(n0 + row) * 1024 + k0 + piece * 8,
                   (char*)Bs + (w * 64 + j * 256) * 16);
    }
    // A: converted regs -> swizzled LDS
    #pragma unroll
    for (int j = 0; j < 2; ++j) {
      int c = tid + j * 256;
      int row = c >> 2, piece = c & 3;
      int swp = piece ^ ((row >> 1) & 3);
      *(f16x8*)&As[row * 32 + swp * 8] = areg[j];
    }
    __syncthreads();

    f16x8 af[4], bf_[4];
    #pragma unroll
    for (int mi = 0; mi < 4; ++mi)
      af[mi] = *(const f16x8*)&As[(wr * 64 + mi * 16 + l15) * 32 + 8 * (hi ^ swr)];
    #pragma unroll
    for (int ni = 0; ni < 4; ++ni)
      bf_[ni] = *(const f16x8*)&Bs[(wc * 64 + ni * 16 + l15) * 32 + 8 * (hi ^ swr)];
    #pragma unroll
    for (int mi = 0; mi < 4; ++mi)
      #pragma unroll
      for (int ni = 0; ni < 4; ++ni)
        acc[mi][ni] = mfma16(af[mi], bf_[ni], acc[mi][ni]);
  }

  #pragma unroll
  for (int mi = 0; mi < 4; ++mi) {
    #pragma unroll
    for (int ni = 0; ni < 4; ++ni) {
      #pragma unroll
      for (int r = 0; r < 4; ++r) {
        const int row = m0 + wr * 64 + mi * 16 + 4 * hi + r;
        const int col = n0 + wc * 64 + ni * 16 + l15;
        float v = acc[mi][ni][r] + ldw(bias, col, f);
        if (vtrans) {
          const int b = row >> 10, sp = row & 1023;
          const int fi = (sp << 10) | col;
          const int h = fi >> 17, s = (fi >> 7) & 1023, d = fi & 127;
          C[(((size_t)(b * 8 + h) * 128 + d) << 10) + s] = (f16)v;
        } else {
          C[(size_t)row * 1024 + col] = (f16)v;
        }
      }
    }
  }
}

// ---------------------------------------------------------------------------
// Output GEMM: out = xb @ WoT^T + bo, written in input dtype.
// ---------------------------------------------------------------------------
__global__ __launch_bounds__(256) void out_gemm_kernel(
    const f16* __restrict__ A, const f16* __restrict__ BT,
    const void* __restrict__ bias, void* __restrict__ C,
    const int* __restrict__ flags) {
  __shared__ __align__(16) f16 As[128 * 32];
  __shared__ __align__(16) f16 Bs[128 * 32];

  const int f = flags[1];
  const int tid = threadIdx.x;
  const int lane = tid & 63, w = tid >> 6;
  const int wr = w >> 1, wc = w & 1;
  const int m0 = blockIdx.y * 128;
  const int n0 = blockIdx.x * 128;
  const int l15 = lane & 15, hi = lane >> 4;
  const int swr = (l15 >> 1) & 3;

  f32x4 acc[4][4];
  #pragma unroll
  for (int i = 0; i < 4; ++i)
    #pragma unroll
    for (int j = 0; j < 4; ++j) acc[i][j] = (f32x4){0.f, 0.f, 0.f, 0.f};

  for (int k0 = 0; k0 < 1024; k0 += 32) {
    if (k0) __syncthreads();
    #pragma unroll
    for (int j = 0; j < 2; ++j) {
      int c = tid + j * 256;
      int cs = c ^ ((c >> 3) & 3);
      int row = cs >> 2, piece = cs & 3;
      async_load16(A  + (size_t)(m0 + row) * 1024 + k0 + piece * 8,
                   (char*)As + (w * 64 + j * 256) * 16);
      async_load16(BT + (size_t)(n0 + row) * 1024 + k0 + piece * 8,
                   (char*)Bs + (w * 64 + j * 256) * 16);
    }
    __syncthreads();

    f16x8 af[4], bf_[4];
    #pragma unroll
    for (int mi = 0; mi < 4; ++mi)
      af[mi] = *(const f16x8*)&As[(wr * 64 + mi * 16 + l15) * 32 + 8 * (hi ^ swr)];
    #pragma unroll
    for (int ni = 0; ni < 4; ++ni)
      bf_[ni] = *(const f16x8*)&Bs[(wc * 64 + ni * 16 + l15) * 32 + 8 * (hi ^ swr)];
    #pragma unroll
    for (int mi = 0; mi < 4; ++mi)
      #pragma unroll
      for (int ni = 0; ni < 4; ++ni)
        acc[mi][ni] = mfma16(af[mi], bf_[ni], acc[mi][ni]);
  }

  #pragma unroll
  for (int mi = 0; mi < 4; ++mi) {
    #pragma unroll
    for (int ni = 0; ni < 4; ++ni) {
      #pragma unroll
      for (int r = 0; r < 4; ++r) {
        const int row = m0 + wr * 64 + mi * 16 + 4 * hi + r;
        const int col = n0 + wc * 64 + ni * 16 + l15;
        float v = acc[mi][ni][r] + ldw(bias, col, f);
        if (f) ((float*)C)[(size_t)row * 1024 + col] = v;
        else   ((__bf16*)C)[(size_t)row * 1024 + col] = (__bf16)v;
      }
    }
  }
}

// ---------------------------------------------------------------------------
// Flash attention per (b,h): Q-tile 128 rows, 8 waves, KV tiles of 64.
// Online softmax with T13 defer-max (THR=8).  LDS 80KB -> 2 blocks/CU.
// Swizzles: Qs/Ks chunk c -> c ^ ((c>>4)&7); Vs/Ps element (row,col) at
// row*64 + ((col>>3)^(row&7))*8 + (col&7).
// ---------------------------------------------------------------------------
__global__ __launch_bounds__(512, 4) void attn_kernel(
    const f16* __restrict__ qbuf, const f16* __restrict__ kbuf,
    const f16* __restrict__ vT, const unsigned long long* __restrict__ mbits,
    f16* __restrict__ xbuf) {
  __shared__ __align__(16) f16 Qs[128 * 128];
  __shared__ __align__(16) f16 Ks[64 * 128];
  __shared__ __align__(16) f16 Vs[128 * 64];   // V^T tile: [d][kv]
  __shared__ __align__(16) f16 Ps[128 * 64];

  const int tid = threadIdx.x, lane = tid & 63, wv = tid >> 6;  // wv 0..7
  const int l15 = lane & 15, hi = lane >> 4;
  const int q0 = blockIdx.x * 128;
  const int h = blockIdx.y, b = blockIdx.z;
  const size_t chunk = (size_t)(b * kH + h) * (kS * kDK);
  const f16* Qg = qbuf + chunk + (size_t)q0 * kDK;
  const f16* Kg = kbuf + chunk;
  const f16* Vg = vT + chunk;                      // rows d (stride kS)
  const unsigned long long* mrow = mbits + (size_t)b * kS * 16;

  // stage Q: 2048 chunks, swizzled source
  #pragma unroll
  for (int j = 0; j < 4; ++j) {
    int c = tid + j * 512;
    int cs = c ^ ((c >> 4) & 7);
    async_load16((const char*)Qg + cs * 16, (char*)Qs + (wv * 64 + j * 512) * 16);
  }

  const float NEG_INF = -__builtin_inff();
  float m_run[4] = {NEG_INF, NEG_INF, NEG_INF, NEG_INF};
  float l_run[4] = {0.f, 0.f, 0.f, 0.f};
  f32x4 acc_o[8];
  #pragma unroll
  for (int j = 0; j < 8; ++j) acc_o[j] = (f32x4){0.f, 0.f, 0.f, 0.f};

  for (int t = 0; t < 16; ++t) {
    const int kv0 = t * 64;
    if (t) __syncthreads();
    #pragma unroll
    for (int j = 0; j < 2; ++j) {                    // K tile: 1024 chunks
      int c = tid + j * 512;
      int cs = c ^ ((c >> 4) & 7);
      async_load16((const char*)Kg + (size_t)kv0 * 256 + cs * 16,
                   (char*)Ks + (wv * 64 + j * 512) * 16);
    }
    #pragma unroll
    for (int j = 0; j < 2; ++j) {                    // V^T tile [128][64]: 1024 chunks
      int c = tid + j * 512;
      int row = c >> 3, piece = (c & 7) ^ (row & 7);
      async_load16((const char*)Vg + ((size_t)row * kS + kv0 + piece * 8) * 2,
                   (char*)Vs + (wv * 64 + j * 512) * 16);
    }
    __syncthreads();

    // S = Q K^T for this wave's 16 rows
    f32x4 accs[4];
    #pragma unroll
    for (int i = 0; i < 4; ++i) accs[i] = (f32x4){0.f, 0.f, 0.f, 0.f};
    const int arow = wv * 16 + l15;
    #pragma unroll
    for (int kk = 0; kk < 4; ++kk) {
      f16x8 aq = *(const f16x8*)&Qs[arow * 128 + (((kk * 4 + hi) ^ (arow & 7)) << 3)];
      #pragma unroll
      for (int ni = 0; ni < 4; ++ni) {
        const int brow = ni * 16 + l15;
        f16x8 bk = *(const f16x8*)&Ks[brow * 128 + (((kk * 4 + hi) ^ (brow & 7)) << 3)];
        accs[ni] = mfma16(aq, bk, accs[ni]);
      }
    }

    // online softmax with defer-max (THR=8)
    #pragma unroll
    for (int r = 0; r < 4; ++r) {
      const int prow = wv * 16 + 4 * hi + r;
      const int qrow = q0 + prow;
      const unsigned long long mw = mrow[(size_t)qrow * 16 + t];
      float sv[4];
      float tmax = NEG_INF;
      #pragma unroll
      for (int ni = 0; ni < 4; ++ni) {
        const int col = ni * 16 + l15;
        const bool on = (mw >> col) & 1ull;
        const float s = on ? accs[ni][r] : NEG_INF;
        sv[ni] = s;
        tmax = fmaxf(tmax, s);
      }
      #pragma unroll
      for (int off = 8; off; off >>= 1) tmax = fmaxf(tmax, __shfl_xor(tmax, off, 64));
      const float mold = m_run[r];
      const bool need = tmax > mold + 8.f;           // T13: rescale only on real growth
      const float mnew = need ? tmax : mold;
      float rsum = 0.f;
      #pragma unroll
      for (int ni = 0; ni < 4; ++ni) {
        const float p = (sv[ni] == NEG_INF) ? 0.f : __expf(sv[ni] - mnew);
        rsum += p;
        const int col = ni * 16 + l15;
        Ps[prow * 64 + (((col >> 3) ^ (prow & 7)) << 3) + (col & 7)] = (f16)p;
      }
      #pragma unroll
      for (int off = 8; off; off >>= 1) rsum += __shfl_xor(rsum, off, 64);
      if (need) {
        const float alpha = __expf(mold - tmax);     // exp(-inf)=0 on first tile
        l_run[r] = l_run[r] * alpha + rsum;
        m_run[r] = mnew;
        #pragma unroll
        for (int nj = 0; nj < 8; ++nj) acc_o[nj][r] *= alpha;
      } else {
        l_run[r] += rsum;
      }
    }

    // O += P @ V
    const int prow2 = wv * 16 + l15;
    #pragma unroll
    for (int kk = 0; kk < 2; ++kk) {
      f16x8 ap = *(const f16x8*)&Ps[prow2 * 64 + (((kk * 4 + hi) ^ (prow2 & 7)) << 3)];
      #pragma unroll
      for (int nj = 0; nj < 8; ++nj) {
        const int vrow = nj * 16 + l15;
        f16x8 bv = *(const f16x8*)&Vs[vrow * 64 + (((kk * 4 + hi) ^ (vrow & 7)) << 3)];
        acc_o[nj] = mfma16(ap, bv, acc_o[nj]);
      }
    }
  }

  #pragma unroll
  for (int r = 0; r < 4; ++r) {
    const float inv = (l_run[r] > 0.f) ? 1.f / l_run[r] : 0.f;
    const int row = q0 + wv * 16 + 4 * hi + r;
    #pragma unroll
    for (int nj = 0; nj < 8; ++nj)
      xbuf[chunk + (size_t)row * kDK + nj * 16 + l15] = (f16)(acc_o[nj][r] * inv);
  }
}

// ---------------------------------------------------------------------------
extern "C" void kernel_launch(void* const* d_in, const int* in_sizes, int n_in,
                              void* d_out, int out_size, void* d_ws, size_t ws_size,
                              hipStream_t stream) {
  const void* query = d_in[0];
  const void* key_  = d_in[1];
  const void* value = d_in[2];
  const void* mask  = d_in[3];
  const void* W_A = d_in[4];
  const void* W_B = d_in[5];
  const void* W_C = d_in[6];
  const void* W_D = d_in[7];
  const void* W_E = d_in[8];
  const void* W_F = d_in[9];
  const void* Wq  = d_in[10];
  const void* bq  = d_in[11];
  const void* Wk  = d_in[12];
  const void* bk  = d_in[13];
  const void* Wv  = d_in[14];
  const void* bv  = d_in[15];
  const void* Wo  = d_in[16];
  const void* bo  = d_in[17];

  char* ws = (char*)d_ws;
  int* flags = (int*)(ws + OFF_FLAG);
  unsigned long long* mbits = (unsigned long long*)(ws + OFF_MBITS);
  f16* WqT = (f16*)(ws + OFF_WQT);
  f16* WkT = (f16*)(ws + OFF_WKT);
  f16* WvT = (f16*)(ws + OFF_WVT);
  f16* WoT = (f16*)(ws + OFF_WOT);
  f16* qb  = (f16*)(ws + OFF_Q);
  f16* kb  = (f16*)(ws + OFF_K);
  f16* vTb = (f16*)(ws + OFF_VT);
  f16* xb  = (f16*)(ws + OFF_X);

  detect_kernel<<<1, 64, 0, stream>>>((const unsigned int*)query,
                                      (const unsigned int*)mask, flags);
  pack_mask_kernel<<<kMaskWords / 4, 256, 0, stream>>>(mask, flags, mbits);
  build_weights_kernel<<<dim3(32, 32, 4), dim3(32, 8), 0, stream>>>(
      Wq, W_A, W_B, Wk, W_C, W_D, Wv, W_E, W_F, Wo, flags, WqT, WkT, WvT, WoT);

  // q/k/v projections with fused input convert; z==2 writes V^T-scattered
  proj_gemm_kernel<<<dim3(8, 64, 3), 256, 0, stream>>>(
      query, key_, value, WqT, WkT, WvT, bq, bk, bv, qb, kb, vTb, flags);

  attn_kernel<<<dim3(8, kH, kB), 512, 0, stream>>>(qb, kb, vTb, mbits, xb);

  out_gemm_kernel<<<dim3(8, 64), 256, 0, stream>>>(xb, WoT, bo, d_out, flags);
}

// Round 7
// 361.024 us; speedup vs baseline: 1.5179x; 1.5179x over previous
//
#include <hip/hip_runtime.h>
#include <hip/hip_bf16.h>
#include <stdint.h>

// ---------------------------------------------------------------------------
// Fused (base+LoRA) QKV projection -> MHA with bool mask -> out proj.
// B=8 S=1024 D=1024 H=8 DK=128 R=16.  Inputs fp32 (device-detected, bf16
// fallback).  Internal pipeline fp16 (bf16 fails absmax: scores sigma~11, no
// 1/sqrt(dk)).  reshape(nb,H,-1,DK) is a FLAT VIEW: head = contiguous chunk.
// R6->R7: revert to R5 structure (R6's launch_bounds(512,4) forced VGPR 64
// vs need 132 -> 68-reg spill, FETCH 140->643MB).  attn: drop sv[] (mask
// in-place) to fit 128 VGPR, declare (256,4) = exactly the 128 cap -> 16
// waves/CU (2x R5); add T13 defer-max (skip O-rescale unless max grows >8).
// ---------------------------------------------------------------------------

#define kB 8
#define kS 1024
#define kD 1024
#define kH 8
#define kDK 128
#define kHDK 1024
#define kM (kB * kS)                       // 8192
#define kMaskWords (kB * kS * (kS / 64))   // 131072 uint64 words
#define kQKVN (kM * kHDK)                  // 8388608 elements

typedef _Float16 f16;
typedef __attribute__((ext_vector_type(4))) float f32x4;
typedef __attribute__((ext_vector_type(8))) _Float16 f16x8;

// ws layout (bytes)
#define OFF_FLAG  ((size_t)0)                                   // flags[0]=mask width, flags[1]=fp32?
#define OFF_MBITS ((size_t)256)
#define OFF_WQT   (OFF_MBITS + (size_t)kMaskWords * 8)
#define OFF_WKT   (OFF_WQT + (size_t)2097152)
#define OFF_WVT   (OFF_WKT + (size_t)2097152)
#define OFF_WOT   (OFF_WVT + (size_t)2097152)
#define OFF_Q     (OFF_WOT + (size_t)2097152)
#define OFF_K     (OFF_Q  + (size_t)kQKVN * 2)
#define OFF_VT    (OFF_K  + (size_t)kQKVN * 2)
#define OFF_X     (OFF_VT + (size_t)kQKVN * 2)
#define OFF_TMP   OFF_X   // f16 input staging; dead before attn writes xb

__device__ __forceinline__ void async_load16(const void* g, void* lds_uniform) {
  auto gp = reinterpret_cast<const __attribute__((address_space(1))) unsigned int*>(
      reinterpret_cast<uintptr_t>(g));
  auto lp = reinterpret_cast<__attribute__((address_space(3))) unsigned int*>(
      reinterpret_cast<uintptr_t>(lds_uniform));
  __builtin_amdgcn_global_load_lds(gp, lp, 16, 0, 0);
}

__device__ __forceinline__ f32x4 mfma16(f16x8 a, f16x8 b, f32x4 c) {
  return __builtin_amdgcn_mfma_f32_16x16x32_f16(a, b, c, 0, 0, 0);
}

// flag-based scalar read of a float tensor that is fp32 (f=1) or bf16 (f=0)
__device__ __forceinline__ float ldw(const void* p, size_t i, int f) {
  return f ? ((const float*)p)[i] : (float)((const __bf16*)p)[i];
}

// ---------------------------------------------------------------------------
// Detect (wave-parallel): flags[1]=fp32?, flags[0]=mask elem width (1/2/4 B).
// ---------------------------------------------------------------------------
__global__ void detect_kernel(const unsigned int* __restrict__ qw,
                              const unsigned int* __restrict__ mw,
                              int* __restrict__ flags) {
  const int lane = threadIdx.x & 63;
  int hi = 0; bool w4 = true, b1 = true;
  #pragma unroll
  for (int j = 0; j < 4; ++j) {
    unsigned int w = qw[lane * 4 + j];
    hi += (int)(((w >> 7) & 0xFF) > 0x90) + (int)(((w >> 23) & 0xFF) > 0x90);
    unsigned int m = mw[lane * 4 + j];
    if (!(m == 0u || m == 1u || m == 0x3F800000u)) w4 = false;
    if ((m & 0xFEFEFEFEu) != 0u) b1 = false;
  }
  #pragma unroll
  for (int off = 32; off; off >>= 1) hi += __shfl_xor(hi, off, 64);
  unsigned long long bw4 = __ballot(w4), bb1 = __ballot(b1);
  if (lane == 0 && blockIdx.x == 0) {
    flags[1] = (hi > 16) ? 1 : 0;
    flags[0] = (bw4 == ~0ull) ? 4 : ((bb1 == ~0ull) ? 1 : 2);
  }
}

// Pack mask into bit-words: word wi covers mask flat elements [wi*64, wi*64+64)
__global__ void pack_mask_kernel(const void* __restrict__ mask, const int* __restrict__ flags,
                                 unsigned long long* __restrict__ mbits) {
  int wi = blockIdx.x * 4 + (threadIdx.x >> 6);
  if (wi >= kMaskWords) return;
  int lane = threadIdx.x & 63;
  size_t e = (size_t)wi * 64 + lane;
  int width = flags[0];
  bool on;
  if (width == 1)      on = ((const unsigned char*)mask)[e] != 0;
  else if (width == 2) on = ((const unsigned short*)mask)[e] != 0;
  else                 on = ((const unsigned int*)mask)[e] != 0;
  unsigned long long bal = __ballot(on);
  if (lane == 0) mbits[wi] = bal;
}

// Convert one float tensor (fp32 or bf16 per flags[1]) to f16 dst.
__global__ __launch_bounds__(256) void convert_kernel(
    const void* __restrict__ src, f16* __restrict__ dst,
    const int* __restrict__ flags, int n) {
  const int i = (blockIdx.x * 256 + threadIdx.x) * 8;
  if (i >= n) return;
  f16x8 o;
  if (flags[1]) {
    f32x4 a = *(const f32x4*)((const float*)src + i);
    f32x4 b = *(const f32x4*)((const float*)src + i + 4);
    #pragma unroll
    for (int j = 0; j < 4; ++j) { o[j] = (f16)a[j]; o[4 + j] = (f16)b[j]; }
  } else {
    const __bf16* s = (const __bf16*)src + i;
    #pragma unroll
    for (int j = 0; j < 8; ++j) o[j] = (f16)(float)s[j];
  }
  *(f16x8*)(dst + i) = o;
}

// ---------------------------------------------------------------------------
// Effective transposed weights: WeffT[n][k] = W[k][n] + sum_r A[k][r]B[r][n]
// ---------------------------------------------------------------------------
__global__ __launch_bounds__(256) void build_weights_kernel(
    const void* __restrict__ Wq, const void* __restrict__ WA, const void* __restrict__ WB,
    const void* __restrict__ Wk, const void* __restrict__ WC, const void* __restrict__ WD,
    const void* __restrict__ Wv, const void* __restrict__ WE, const void* __restrict__ WF,
    const void* __restrict__ Wo, const int* __restrict__ flags,
    f16* __restrict__ WqT, f16* __restrict__ WkT,
    f16* __restrict__ WvT, f16* __restrict__ WoT) {
  const int z = blockIdx.z;
  const int f = flags[1];
  const void *W, *Aw = nullptr, *Bw = nullptr;
  f16* Out;
  if (z == 0)      { W = Wq; Aw = WA; Bw = WB; Out = WqT; }
  else if (z == 1) { W = Wk; Aw = WC; Bw = WD; Out = WkT; }
  else if (z == 2) { W = Wv; Aw = WE; Bw = WF; Out = WvT; }
  else             { W = Wo;                   Out = WoT; }

  __shared__ float Wt[32][33];
  __shared__ float At[32][16];
  __shared__ float Bt[16][33];
  const int tx = threadIdx.x, ty = threadIdx.y;     // block (32,8)
  const int k0 = blockIdx.y * 32, n0 = blockIdx.x * 32;
  #pragma unroll
  for (int i = 0; i < 4; ++i)
    Wt[ty + 8 * i][tx] = ldw(W, (size_t)(k0 + ty + 8 * i) * 1024 + n0 + tx, f);
  const int t = ty * 32 + tx;
  if (Aw) {
    #pragma unroll
    for (int j = 0; j < 2; ++j) {
      int e = t + j * 256;                          // 512 elems: 32x16
      At[e >> 4][e & 15] = ldw(Aw, (size_t)(k0 + (e >> 4)) * 16 + (e & 15), f);
    }
    #pragma unroll
    for (int j = 0; j < 2; ++j) {
      int e = t + j * 256;                          // 512 elems: 16x32
      Bt[e >> 5][e & 31] = ldw(Bw, (size_t)(e >> 5) * 1024 + n0 + (e & 31), f);
    }
  }
  __syncthreads();
  #pragma unroll
  for (int i = 0; i < 4; ++i) {
    const int nloc = ty + 8 * i, kloc = tx;
    float acc = Wt[kloc][nloc];
    if (Aw) {
      #pragma unroll
      for (int r = 0; r < 16; ++r) acc += At[kloc][r] * Bt[r][nloc];
    }
    Out[(size_t)(n0 + nloc) * 1024 + k0 + kloc] = (f16)acc;
  }
}

// ---------------------------------------------------------------------------
// GEMM: C[M,N] = A[M,K] @ BT[N,K]^T + bias.  128x128 tile, BK=32, 4 waves.
// LDS tiles [128][32] f16, swizzle: chunk c -> c ^ ((c>>3)&3).
// ---------------------------------------------------------------------------
__global__ __launch_bounds__(256) void gemm_bt_kernel(
    const f16* __restrict__ A, const f16* __restrict__ BT,
    const void* __restrict__ bias, void* __restrict__ C,
    const int* __restrict__ flags, int vtrans, int out_dyn,
    int M, int N, int K) {
  __shared__ __align__(16) f16 As[128 * 32];
  __shared__ __align__(16) f16 Bs[128 * 32];

  const int f = flags[1];
  const int tid = threadIdx.x;
  const int lane = tid & 63, w = tid >> 6;
  const int wr = w >> 1, wc = w & 1;
  const int m0 = blockIdx.y * 128;
  const int n0 = blockIdx.x * 128;
  const int l15 = lane & 15, hi = lane >> 4;
  const int swr = (l15 >> 1) & 3;                 // read-side XOR value

  f32x4 acc[4][4];
  #pragma unroll
  for (int i = 0; i < 4; ++i)
    #pragma unroll
    for (int j = 0; j < 4; ++j) acc[i][j] = (f32x4){0.f, 0.f, 0.f, 0.f};

  for (int k0 = 0; k0 < K; k0 += 32) {
    if (k0) __syncthreads();
    #pragma unroll
    for (int j = 0; j < 2; ++j) {
      int c = tid + j * 256;
      int cs = c ^ ((c >> 3) & 3);              // pre-swizzled source chunk
      int row = cs >> 2, piece = cs & 3;
      async_load16(A  + (size_t)(m0 + row) * K + k0 + piece * 8,
                   (char*)As + (w * 64 + j * 256) * 16);
      async_load16(BT + (size_t)(n0 + row) * K + k0 + piece * 8,
                   (char*)Bs + (w * 64 + j * 256) * 16);
    }
    __syncthreads();

    f16x8 af[4], bf_[4];
    #pragma unroll
    for (int mi = 0; mi < 4; ++mi)
      af[mi] = *(const f16x8*)&As[(wr * 64 + mi * 16 + l15) * 32 + 8 * (hi ^ swr)];
    #pragma unroll
    for (int ni = 0; ni < 4; ++ni)
      bf_[ni] = *(const f16x8*)&Bs[(wc * 64 + ni * 16 + l15) * 32 + 8 * (hi ^ swr)];
    #pragma unroll
    for (int mi = 0; mi < 4; ++mi)
      #pragma unroll
      for (int ni = 0; ni < 4; ++ni)
        acc[mi][ni] = mfma16(af[mi], bf_[ni], acc[mi][ni]);
  }

  const int wf32 = out_dyn && f;
  #pragma unroll
  for (int mi = 0; mi < 4; ++mi) {
    #pragma unroll
    for (int ni = 0; ni < 4; ++ni) {
      #pragma unroll
      for (int r = 0; r < 4; ++r) {
        const int row = m0 + wr * 64 + mi * 16 + 4 * hi + r;
        const int col = n0 + wc * 64 + ni * 16 + l15;
        float v = acc[mi][ni][r] + (bias ? ldw(bias, col, f) : 0.f);
        if (vtrans) {
          // scatter into V^T[b][h][d][s]: flat-view remap of (row,col)
          const int b = row >> 10, sp = row & 1023;
          const int fi = (sp << 10) | col;
          const int h = fi >> 17, s = (fi >> 7) & 1023, d = fi & 127;
          ((f16*)C)[(((size_t)(b * 8 + h) * 128 + d) << 10) + s] = (f16)v;
        } else if (wf32) {
          ((float*)C)[(size_t)row * N + col] = v;
        } else if (out_dyn) {
          ((__bf16*)C)[(size_t)row * N + col] = (__bf16)v;
        } else {
          ((f16*)C)[(size_t)row * N + col] = (f16)v;
        }
      }
    }
  }
}

// ---------------------------------------------------------------------------
// Flash attention per (b,h): Q-tile 64 rows, 4 waves, KV tiles of 64.
// T13 defer-max (THR=8).  VGPR capped at 128 via (256,4) -> 16 waves/CU.
// Swizzles: Qs/Ks chunk c -> c ^ ((c>>4)&7); Vs/Ps element (row,col) at
// row*64 + ((col>>3)^(row&7))*8 + (col&7).
// ---------------------------------------------------------------------------
__global__ __launch_bounds__(256, 4) void attn_kernel(
    const f16* __restrict__ qbuf, const f16* __restrict__ kbuf,
    const f16* __restrict__ vT, const unsigned long long* __restrict__ mbits,
    f16* __restrict__ xbuf) {
  __shared__ __align__(16) f16 Qs[64 * 128];
  __shared__ __align__(16) f16 Ks[64 * 128];
  __shared__ __align__(16) f16 Vs[128 * 64];   // V^T tile: [d][kv]
  __shared__ __align__(16) f16 Ps[64 * 64];

  const int tid = threadIdx.x, lane = tid & 63, wv = tid >> 6;
  const int l15 = lane & 15, hi = lane >> 4;
  const int q0 = blockIdx.x * 64;
  const int h = blockIdx.y, b = blockIdx.z;
  const size_t chunk = (size_t)(b * kH + h) * (kS * kDK);
  const f16* Qg = qbuf + chunk + (size_t)q0 * kDK;
  const f16* Kg = kbuf + chunk;
  const f16* Vg = vT + chunk;                      // rows d (stride kS)
  const unsigned long long* mrow = mbits + (size_t)b * kS * 16;

  // stage Q: LDS chunk c <- global chunk c ^ ((c>>4)&7)
  #pragma unroll
  for (int j = 0; j < 4; ++j) {
    int c = tid + j * 256;
    int cs = c ^ ((c >> 4) & 7);
    async_load16((const char*)Qg + cs * 16, (char*)Qs + (wv * 64 + j * 256) * 16);
  }

  const float NEG_INF = -__builtin_inff();
  float m_run[4] = {NEG_INF, NEG_INF, NEG_INF, NEG_INF};
  float l_run[4] = {0.f, 0.f, 0.f, 0.f};
  f32x4 acc_o[8];
  #pragma unroll
  for (int j = 0; j < 8; ++j) acc_o[j] = (f32x4){0.f, 0.f, 0.f, 0.f};

  for (int t = 0; t < 16; ++t) {
    const int kv0 = t * 64;
    if (t) __syncthreads();
    #pragma unroll
    for (int j = 0; j < 4; ++j) {                    // K tile
      int c = tid + j * 256;
      int cs = c ^ ((c >> 4) & 7);
      async_load16((const char*)Kg + (size_t)kv0 * 256 + cs * 16,
                   (char*)Ks + (wv * 64 + j * 256) * 16);
    }
    #pragma unroll
    for (int j = 0; j < 4; ++j) {                    // V^T tile [128][64]
      int c = tid + j * 256;
      int row = c >> 3, piece = (c & 7) ^ (row & 7);
      async_load16((const char*)Vg + ((size_t)row * kS + kv0 + piece * 8) * 2,
                   (char*)Vs + (wv * 64 + j * 256) * 16);
    }
    __syncthreads();

    f32x4 accs[4];
    #pragma unroll
    for (int i = 0; i < 4; ++i) accs[i] = (f32x4){0.f, 0.f, 0.f, 0.f};
    const int arow = wv * 16 + l15;
    #pragma unroll
    for (int kk = 0; kk < 4; ++kk) {
      f16x8 aq = *(const f16x8*)&Qs[arow * 128 + (((kk * 4 + hi) ^ (arow & 7)) << 3)];
      #pragma unroll
      for (int ni = 0; ni < 4; ++ni) {
        const int brow = ni * 16 + l15;
        f16x8 bk = *(const f16x8*)&Ks[brow * 128 + (((kk * 4 + hi) ^ (brow & 7)) << 3)];
        accs[ni] = mfma16(aq, bk, accs[ni]);
      }
    }

    // online softmax with T13 defer-max; mask applied in-place into accs
    #pragma unroll
    for (int r = 0; r < 4; ++r) {
      const int prow = wv * 16 + 4 * hi + r;
      const int qrow = q0 + prow;
      const unsigned long long mw = mrow[(size_t)qrow * 16 + t];
      float tmax = NEG_INF;
      #pragma unroll
      for (int ni = 0; ni < 4; ++ni) {
        const int col = ni * 16 + l15;
        const bool on = (mw >> col) & 1ull;
        accs[ni][r] = on ? accs[ni][r] : NEG_INF;
        tmax = fmaxf(tmax, accs[ni][r]);
      }
      #pragma unroll
      for (int off = 8; off; off >>= 1) tmax = fmaxf(tmax, __shfl_xor(tmax, off, 64));
      const float mold = m_run[r];
      const bool need = tmax > mold + 8.f;           // defer rescale
      const float mnew = need ? tmax : mold;
      float rsum = 0.f;
      #pragma unroll
      for (int ni = 0; ni < 4; ++ni) {
        const float p = (accs[ni][r] == NEG_INF) ? 0.f : __expf(accs[ni][r] - mnew);
        rsum += p;
        const int col = ni * 16 + l15;
        Ps[prow * 64 + (((col >> 3) ^ (prow & 7)) << 3) + (col & 7)] = (f16)p;
      }
      #pragma unroll
      for (int off = 8; off; off >>= 1) rsum += __shfl_xor(rsum, off, 64);
      if (need) {
        const float alpha = __expf(mold - tmax);     // exp(-inf)=0 on first tile
        l_run[r] = l_run[r] * alpha + rsum;
        m_run[r] = mnew;
        #pragma unroll
        for (int nj = 0; nj < 8; ++nj) acc_o[nj][r] *= alpha;
      } else {
        l_run[r] += rsum;
      }
    }

    const int prow2 = wv * 16 + l15;
    #pragma unroll
    for (int kk = 0; kk < 2; ++kk) {
      f16x8 ap = *(const f16x8*)&Ps[prow2 * 64 + (((kk * 4 + hi) ^ (prow2 & 7)) << 3)];
      #pragma unroll
      for (int nj = 0; nj < 8; ++nj) {
        const int vrow = nj * 16 + l15;
        f16x8 bv = *(const f16x8*)&Vs[vrow * 64 + (((kk * 4 + hi) ^ (vrow & 7)) << 3)];
        acc_o[nj] = mfma16(ap, bv, acc_o[nj]);
      }
    }
  }

  #pragma unroll
  for (int r = 0; r < 4; ++r) {
    const float inv = (l_run[r] > 0.f) ? 1.f / l_run[r] : 0.f;
    const int row = q0 + wv * 16 + 4 * hi + r;
    #pragma unroll
    for (int nj = 0; nj < 8; ++nj)
      xbuf[chunk + (size_t)row * kDK + nj * 16 + l15] = (f16)(acc_o[nj][r] * inv);
  }
}

// ---------------------------------------------------------------------------
extern "C" void kernel_launch(void* const* d_in, const int* in_sizes, int n_in,
                              void* d_out, int out_size, void* d_ws, size_t ws_size,
                              hipStream_t stream) {
  const void* query = d_in[0];
  const void* key_  = d_in[1];
  const void* value = d_in[2];
  const void* mask  = d_in[3];
  const void* W_A = d_in[4];
  const void* W_B = d_in[5];
  const void* W_C = d_in[6];
  const void* W_D = d_in[7];
  const void* W_E = d_in[8];
  const void* W_F = d_in[9];
  const void* Wq  = d_in[10];
  const void* bq  = d_in[11];
  const void* Wk  = d_in[12];
  const void* bk  = d_in[13];
  const void* Wv  = d_in[14];
  const void* bv  = d_in[15];
  const void* Wo  = d_in[16];
  const void* bo  = d_in[17];

  char* ws = (char*)d_ws;
  int* flags = (int*)(ws + OFF_FLAG);
  unsigned long long* mbits = (unsigned long long*)(ws + OFF_MBITS);
  f16* WqT = (f16*)(ws + OFF_WQT);
  f16* WkT = (f16*)(ws + OFF_WKT);
  f16* WvT = (f16*)(ws + OFF_WVT);
  f16* WoT = (f16*)(ws + OFF_WOT);
  f16* qb  = (f16*)(ws + OFF_Q);
  f16* kb  = (f16*)(ws + OFF_K);
  f16* vTb = (f16*)(ws + OFF_VT);
  f16* xb  = (f16*)(ws + OFF_X);
  f16* tmp = (f16*)(ws + OFF_TMP);   // aliases xb; dead before attn

  detect_kernel<<<1, 64, 0, stream>>>((const unsigned int*)query,
                                      (const unsigned int*)mask, flags);
  pack_mask_kernel<<<kMaskWords / 4, 256, 0, stream>>>(mask, flags, mbits);
  build_weights_kernel<<<dim3(32, 32, 4), dim3(32, 8), 0, stream>>>(
      Wq, W_A, W_B, Wk, W_C, W_D, Wv, W_E, W_F, Wo, flags, WqT, WkT, WvT, WoT);

  // projections (tmp reused sequentially; stream order serializes)
  convert_kernel<<<kQKVN / (256 * 8), 256, 0, stream>>>(query, tmp, flags, kQKVN);
  gemm_bt_kernel<<<dim3(8, 64), 256, 0, stream>>>(
      tmp, WqT, bq, qb, flags, /*vtrans=*/0, /*out_dyn=*/0, kM, kHDK, kD);
  convert_kernel<<<kQKVN / (256 * 8), 256, 0, stream>>>(key_, tmp, flags, kQKVN);
  gemm_bt_kernel<<<dim3(8, 64), 256, 0, stream>>>(
      tmp, WkT, bk, kb, flags, 0, 0, kM, kHDK, kD);
  convert_kernel<<<kQKVN / (256 * 8), 256, 0, stream>>>(value, tmp, flags, kQKVN);
  gemm_bt_kernel<<<dim3(8, 64), 256, 0, stream>>>(
      tmp, WvT, bv, vTb, flags, /*vtrans=*/1, 0, kM, kHDK, kD);

  attn_kernel<<<dim3(16, kH, kB), 256, 0, stream>>>(qb, kb, vTb, mbits, xb);

  gemm_bt_kernel<<<dim3(8, 64), 256, 0, stream>>>(
      xb, WoT, bo, d_out, flags, 0, /*out_dyn=*/1, kM, kD, kHDK);
}